// Round 7
// baseline (188.979 us; speedup 1.0000x reference)
//
#include <hip/hip_runtime.h>

typedef _Float16 f16x8 __attribute__((ext_vector_type(8)));
typedef float f32x4 __attribute__((ext_vector_type(4)));

#define B_  8
#define LQ  2048
#define LC  4096
#define DD  256

// f32 -> f16 convert of query (8 floats/thread, exact coverage of 4,194,304).
__global__ __launch_bounds__(256)
void convert_q(const float* __restrict__ q, _Float16* __restrict__ qf) {
    const size_t i = ((size_t)blockIdx.x * 256 + threadIdx.x) * 8;
    const f32x4 v0 = *(const f32x4*)(q + i);
    const f32x4 v1 = *(const f32x4*)(q + i + 4);
    f16x8 o;
#pragma unroll
    for (int e = 0; e < 4; ++e) { o[e] = (_Float16)v0[e]; o[e + 4] = (_Float16)v1[e]; }
    *(f16x8*)(qf + i) = o;
}

// One block per (b, 128-ctx tile, 1024-q half). Grid is (b, x) so batch->XCD
// is fixed (linear id = x*8+b, round-robin over 8 XCDs) -> qf[b] hot in L2.
// A (ctx): f32 -> f16 -> swizzled LDS once (ONE barrier in the whole kernel).
// B (query): f16 fragments global->VGPR, depth-3 register ring, NO LDS, NO
// explicit waitcnt/sched_barrier — compiler emits fine-grained vmcnt.
// 16x16x32 f16 MFMA, 4x4 frags/wave. Writes sp[b][nh][c] = max over 1024 q.
__global__ __launch_bounds__(256, 2)
void gemm_max_kernel(const _Float16* __restrict__ qf, const float* __restrict__ ctx,
                     float* __restrict__ sp, float* __restrict__ out) {
    __shared__ __align__(16) _Float16 As[128 * 256];   // 64 KB swizzled A tile
    __shared__ float red[256];

    const int b    = blockIdx.x;     // batch 0..7  (fast dim -> XCD affinity)
    const int x    = blockIdx.y;     // mt*2 + nh, 0..63
    const int mt   = x >> 1;
    const int nh   = x & 1;
    const int tid  = threadIdx.x;
    const int lane = tid & 63;
    const int wave = tid >> 6;
    const int wm   = wave >> 1;
    const int wn   = wave & 1;
    const int quad = lane >> 4;
    const int l15  = lane & 15;

    if (x == 0) out[b * DD + tid] = 0.f;   // zero for kernel2's atomics

    // ---- stage A tile: f32 global -> f16 -> swizzled LDS (validated in R5).
    // row r, 16B-group kg at LDS pos kg holds global group (kg&16)|((kg&15)^(r&15)).
    {
        const float* Ag = ctx + ((size_t)(b * LC + mt * 128)) * DD;
        const int rsub = tid >> 5;         // 0..7
        const int kg   = tid & 31;
#pragma unroll
        for (int p = 0; p < 16; ++p) {
            const int row = p * 8 + rsub;
            const int kgg = (kg & 16) | ((kg & 15) ^ (row & 15));
            const float* s = Ag + (size_t)row * DD + kgg * 8;
            const f32x4 v0 = *(const f32x4*)(s);
            const f32x4 v1 = *(const f32x4*)(s + 4);
            f16x8 o;
#pragma unroll
            for (int e = 0; e < 4; ++e) { o[e] = (_Float16)v0[e]; o[e + 4] = (_Float16)v1[e]; }
            *(f16x8*)((char*)As + row * 512 + kg * 16) = o;
        }
    }
    __syncthreads();   // the only barrier before the epilogue

    // ---- B fragment register ring, depth 3 (ring of 4).
    // Step s = nt*8 + ksl: q rows nh*1024 + nt*128 + wn*64 + ni*16 + l15,
    // k = (s&7)*32 + quad*8 .. +8. 16 B per lane (validated address math in R5).
    const _Float16* Bbase = qf +
        ((size_t)(b * LQ + nh * 1024 + wn * 64 + l15)) * DD + quad * 8;
    f16x8 bf[4][4];
    #define BLOAD(s, ring)                                                        \
        {                                                                         \
            const _Float16* _p = Bbase + (size_t)((s) >> 3) * (128 * DD)          \
                                       + ((s) & 7) * 32;                          \
            _Pragma("unroll")                                                     \
            for (int ni = 0; ni < 4; ++ni)                                        \
                bf[ring][ni] = *(const f16x8*)(_p + (size_t)ni * 16 * DD);        \
        }
    BLOAD(0, 0)
    BLOAD(1, 1)
    BLOAD(2, 2)

    float rm[4][4];
#pragma unroll
    for (int mi = 0; mi < 4; ++mi)
#pragma unroll
        for (int r = 0; r < 4; ++r)
            rm[mi][r] = -3.4e38f;

#pragma unroll 1
    for (int nt = 0; nt < 8; ++nt) {
        f32x4 acc[4][4];
#pragma unroll
        for (int mi = 0; mi < 4; ++mi)
#pragma unroll
            for (int ni = 0; ni < 4; ++ni)
                acc[mi][ni] = (f32x4)0.0f;

#pragma unroll
        for (int ksl = 0; ksl < 8; ++ksl) {
            const int s = nt * 8 + ksl;
            if (s + 3 < 64) BLOAD(s + 3, (ksl + 3) & 3)

            f16x8 afr[4];
            const int kg = ksl * 4 + quad;
#pragma unroll
            for (int mi = 0; mi < 4; ++mi) {
                const int row = wm * 64 + mi * 16 + l15;
                const int pos = (kg & 16) | ((kg & 15) ^ (row & 15));
                afr[mi] = *(const f16x8*)((const char*)As + row * 512 + pos * 16);
            }
#pragma unroll
            for (int mi = 0; mi < 4; ++mi)
#pragma unroll
                for (int ni = 0; ni < 4; ++ni)
                    acc[mi][ni] = __builtin_amdgcn_mfma_f32_16x16x32_f16(
                        afr[mi], bf[ksl & 3][ni], acc[mi][ni], 0, 0, 0);
        }
        // fold this q-tile into the running row max (pure VALU, registers)
#pragma unroll
        for (int mi = 0; mi < 4; ++mi)
#pragma unroll
            for (int r = 0; r < 4; ++r)
                rm[mi][r] = fmaxf(rm[mi][r],
                                  fmaxf(fmaxf(acc[mi][0][r], acc[mi][1][r]),
                                        fmaxf(acc[mi][2][r], acc[mi][3][r])));
    }
    #undef BLOAD

    // ---- epilogue ONCE: reduce over 16 q-col lanes, then the two wn halves
#pragma unroll
    for (int sh = 1; sh <= 8; sh <<= 1)
#pragma unroll
        for (int mi = 0; mi < 4; ++mi)
#pragma unroll
            for (int r = 0; r < 4; ++r)
                rm[mi][r] = fmaxf(rm[mi][r], __shfl_xor(rm[mi][r], sh, 64));

    if (l15 == 0) {
#pragma unroll
        for (int mi = 0; mi < 4; ++mi)
#pragma unroll
            for (int r = 0; r < 4; ++r)
                red[wn * 128 + wm * 64 + mi * 16 + quad * 4 + r] = rm[mi][r];
    }
    __syncthreads();
    if (tid < 128)
        sp[((size_t)b * 2 + nh) * LC + mt * 128 + tid] =
            fmaxf(red[tid], red[128 + tid]);
}

// 256 blocks (b fast dim -> XCD affinity). Each redundantly computes the batch
// softmax stats from sp, then a 128-ctx slice of the weighted sum (f32 ctx,
// fully coalesced), one atomicAdd per out element.
__global__ __launch_bounds__(256)
void softmax_out_kernel(const float* __restrict__ sp, const float* __restrict__ ctx,
                        float* __restrict__ out) {
    __shared__ float pr[128];
    __shared__ float part[4][256];
    __shared__ float rsc[8];

    const int b    = blockIdx.x;
    const int ch   = blockIdx.y;   // 0..31
    const int tid  = threadIdx.x;
    const int lane = tid & 63;
    const int wave = tid >> 6;
    const float* sp0 = sp + (size_t)b * 2 * LC;
    const float* sp1 = sp0 + LC;

    float sv[16];
    float lmax = -3.4e38f;
#pragma unroll
    for (int j = 0; j < 16; ++j) {
        const int c = j * 256 + tid;
        sv[j] = fmaxf(sp0[c], sp1[c]);
        lmax  = fmaxf(lmax, sv[j]);
    }
#pragma unroll
    for (int sh = 1; sh < 64; sh <<= 1)
        lmax = fmaxf(lmax, __shfl_xor(lmax, sh, 64));
    if (lane == 0) rsc[wave] = lmax;
    __syncthreads();
    const float M = fmaxf(fmaxf(rsc[0], rsc[1]), fmaxf(rsc[2], rsc[3]));

    float lsum = 0.f;
#pragma unroll
    for (int j = 0; j < 16; ++j) lsum += __expf(sv[j] - M);
#pragma unroll
    for (int sh = 1; sh < 64; sh <<= 1)
        lsum += __shfl_xor(lsum, sh, 64);
    if (lane == 0) rsc[4 + wave] = lsum;
    if (tid < 128) {
        const int c = ch * 128 + tid;
        pr[tid] = __expf(fmaxf(sp0[c], sp1[c]) - M);
    }
    __syncthreads();
    const float inv = 1.f / (rsc[4] + rsc[5] + rsc[6] + rsc[7]);

    // rows [ch*128, +128): wave w takes rows w, w+4, ...; lane covers 4 d-cols.
    const float* cb = ctx + ((size_t)(b * LC + ch * 128)) * DD + lane * 4;
    f32x4 acc = (f32x4)0.0f;
#pragma unroll 8
    for (int i = wave; i < 128; i += 4)
        acc += pr[i] * *(const f32x4*)(cb + (size_t)i * DD);
#pragma unroll
    for (int e = 0; e < 4; ++e) part[wave][lane * 4 + e] = acc[e];
    __syncthreads();
    atomicAdd(&out[b * DD + tid],
              (part[0][tid] + part[1][tid] + part[2][tid] + part[3][tid]) * inv);
}

extern "C" void kernel_launch(void* const* d_in, const int* in_sizes, int n_in,
                              void* d_out, int out_size, void* d_ws, size_t ws_size,
                              hipStream_t stream) {
    const float* q   = (const float*)d_in[0];   // [8, 2048, 256] f32
    const float* ctx = (const float*)d_in[1];   // [8, 4096, 256] f32
    float* out = (float*)d_out;                 // [8, 1, 256] f32

    // ws: qf @0 (8,388,608 B), sp @8388608 (8*2*4096*4 = 262,144 B)
    char* ws = (char*)d_ws;
    _Float16* qf = (_Float16*)(ws);
    float* sp    = (float*)(ws + 8388608);

    convert_q<<<2048, 256, 0, stream>>>(q, qf);
    gemm_max_kernel<<<dim3(8, 64), 256, 0, stream>>>(qf, ctx, sp, out);
    softmax_out_kernel<<<dim3(8, 32), 256, 0, stream>>>(sp, ctx, out);
}